// Round 1
// baseline (12134.966 us; speedup 1.0000x reference)
//
#include <hip/hip_runtime.h>
#include <math.h>

#define LAYERS 2
#define B_ 2
#define S_ 1024
#define D_ 2048
#define F_ 5504
#define R_ 8
#define H_ 16
#define DH_ 128
#define M_ (B_*S_)   // 2048

// ---------------------------------------------------------------------------
// NF4 dequant helper: exactly replicates
//   idx = searchsorted(mids, v/max(amax,1e-12), side='left'); codes[idx]*amax
// via a compare/select chain (count of mids strictly less than normed).
// ---------------------------------------------------------------------------
__device__ __forceinline__ float nf4_deq(float v, float amax) {
    const float C0  = -1.0f;
    const float C1  = -0.6961928009986877f;
    const float C2  = -0.5250730514526367f;
    const float C3  = -0.39491748809814453f;
    const float C4  = -0.28444138169288635f;
    const float C5  = -0.18477343022823334f;
    const float C6  = -0.09105003625154495f;
    const float C7  = 0.0f;
    const float C8  = 0.07958029955625534f;
    const float C9  = 0.16093020141124725f;
    const float C10 = 0.24611230194568634f;
    const float C11 = 0.33791524171829224f;
    const float C12 = 0.44070982933044434f;
    const float C13 = 0.5626170039176941f;
    const float C14 = 0.7229568362236023f;
    const float C15 = 1.0f;
    float normed = v / fmaxf(amax, 1e-12f);
    float c = C0;
    c = (normed > 0.5f*(C0 +C1 )) ? C1  : c;
    c = (normed > 0.5f*(C1 +C2 )) ? C2  : c;
    c = (normed > 0.5f*(C2 +C3 )) ? C3  : c;
    c = (normed > 0.5f*(C3 +C4 )) ? C4  : c;
    c = (normed > 0.5f*(C4 +C5 )) ? C5  : c;
    c = (normed > 0.5f*(C5 +C6 )) ? C6  : c;
    c = (normed > 0.5f*(C6 +C7 )) ? C7  : c;
    c = (normed > 0.5f*(C7 +C8 )) ? C8  : c;
    c = (normed > 0.5f*(C8 +C9 )) ? C9  : c;
    c = (normed > 0.5f*(C9 +C10)) ? C10 : c;
    c = (normed > 0.5f*(C10+C11)) ? C11 : c;
    c = (normed > 0.5f*(C11+C12)) ? C12 : c;
    c = (normed > 0.5f*(C12+C13)) ? C13 : c;
    c = (normed > 0.5f*(C13+C14)) ? C14 : c;
    c = (normed > 0.5f*(C14+C15)) ? C15 : c;
    return c * amax;
}

__device__ __forceinline__ float silu_f(float x) { return x / (1.0f + expf(-x)); }

// ---------------------------------------------------------------------------
// Per-64-block absmax of a weight tensor (flat).
// ---------------------------------------------------------------------------
__global__ void absmax_kernel(const float* __restrict__ w, float* __restrict__ amax, int nblk) {
    int i = blockIdx.x * 256 + threadIdx.x;
    if (i >= nblk) return;
    const float* p = w + (size_t)i * 64;
    float m = 0.0f;
    #pragma unroll 8
    for (int j = 0; j < 64; ++j) m = fmaxf(m, fabsf(p[j]));
    amax[i] = m;
}

// ---------------------------------------------------------------------------
// RMSNorm: one block per row of D_ elements.
// ---------------------------------------------------------------------------
__global__ __launch_bounds__(256) void rmsnorm_kernel(const float* __restrict__ x,
                                                      const float* __restrict__ w,
                                                      float* __restrict__ out) {
    int row = blockIdx.x;
    const float* xr = x + (size_t)row * D_;
    float ss = 0.0f;
    for (int k = threadIdx.x; k < D_; k += 256) { float v = xr[k]; ss += v * v; }
    __shared__ float red[256];
    red[threadIdx.x] = ss; __syncthreads();
    for (int s = 128; s > 0; s >>= 1) {
        if (threadIdx.x < s) red[threadIdx.x] += red[threadIdx.x + s];
        __syncthreads();
    }
    float scale = 1.0f / sqrtf(red[0] / (float)D_ + 1e-5f);
    for (int k = threadIdx.x; k < D_; k += 256)
        out[(size_t)row * D_ + k] = xr[k] * scale * w[k];
}

// ---------------------------------------------------------------------------
// LoRA A-projection: tA[m][r] = sum_k h[m,k] * A[r,k].  One block per row m.
// ---------------------------------------------------------------------------
__global__ __launch_bounds__(256) void lora_a_kernel(const float* __restrict__ h,
                                                     const float* __restrict__ A,
                                                     float* __restrict__ tA) {
    int m = blockIdx.x;
    const float* hr = h + (size_t)m * D_;
    float acc[R_];
    #pragma unroll
    for (int r = 0; r < R_; ++r) acc[r] = 0.0f;
    for (int k = threadIdx.x; k < D_; k += 256) {
        float hv = hr[k];
        #pragma unroll
        for (int r = 0; r < R_; ++r) acc[r] += hv * A[(size_t)r * D_ + k];
    }
    __shared__ float red[256];
    for (int r = 0; r < R_; ++r) {
        red[threadIdx.x] = acc[r]; __syncthreads();
        for (int s = 128; s > 0; s >>= 1) {
            if (threadIdx.x < s) red[threadIdx.x] += red[threadIdx.x + s];
            __syncthreads();
        }
        if (threadIdx.x == 0) tA[(size_t)m * R_ + r] = red[0];
        __syncthreads();
    }
}

// ---------------------------------------------------------------------------
// GEMM: Y[m,n] = sum_k X[m,k]*deq(W[n,k]) [+ 2.0*sum_r tA[m,r]*lB[n,r]]
//               [+ resid[m,n]] [silu]
// 128x128 tile, BK=8, 256 threads, 8x8 microtile (split 4+4).
// M,N,K all multiples of 128/8 in this problem (no edge guards needed).
// ---------------------------------------------------------------------------
template<int ACT, bool HAS_LORA, bool HAS_RESID>
__global__ __launch_bounds__(256) void gemm_qlora_kernel(
        const float* __restrict__ X, const float* __restrict__ W,
        const float* __restrict__ Amax,
        const float* __restrict__ tA, const float* __restrict__ lB,
        const float* __restrict__ resid, float* __restrict__ Y,
        int Mdim, int Ndim, int Kdim) {
    const int tid = threadIdx.x;
    const int bn = blockIdx.x, bm = blockIdx.y;
    const int tx = tid & 15, ty = tid >> 4;

    __shared__ __align__(16) float Xs[8][132];
    __shared__ __align__(16) float Ws[8][132];

    float c[8][8];
    #pragma unroll
    for (int i = 0; i < 8; ++i)
        #pragma unroll
        for (int j = 0; j < 8; ++j) c[i][j] = 0.0f;

    const int nKB = Kdim >> 6;
    const int ld_row = tid >> 1;       // 0..127
    const int ld_k   = (tid & 1) * 4;  // 0 or 4
    const float* Xrow = X + (size_t)(bm * 128 + ld_row) * Kdim + ld_k;
    const float* Wrow = W + (size_t)(bn * 128 + ld_row) * Kdim + ld_k;
    const float* Arow = Amax + (size_t)(bn * 128 + ld_row) * nKB;

    for (int kt = 0; kt < Kdim; kt += 8) {
        float4 xv = *(const float4*)(Xrow + kt);
        float4 wv = *(const float4*)(Wrow + kt);
        float am = Arow[(kt + ld_k) >> 6];
        wv.x = nf4_deq(wv.x, am);
        wv.y = nf4_deq(wv.y, am);
        wv.z = nf4_deq(wv.z, am);
        wv.w = nf4_deq(wv.w, am);
        __syncthreads();
        Xs[ld_k + 0][ld_row] = xv.x;
        Xs[ld_k + 1][ld_row] = xv.y;
        Xs[ld_k + 2][ld_row] = xv.z;
        Xs[ld_k + 3][ld_row] = xv.w;
        Ws[ld_k + 0][ld_row] = wv.x;
        Ws[ld_k + 1][ld_row] = wv.y;
        Ws[ld_k + 2][ld_row] = wv.z;
        Ws[ld_k + 3][ld_row] = wv.w;
        __syncthreads();
        #pragma unroll
        for (int k = 0; k < 8; ++k) {
            float4 a0 = *(const float4*)&Xs[k][ty * 4];
            float4 a1 = *(const float4*)&Xs[k][64 + ty * 4];
            float4 b0 = *(const float4*)&Ws[k][tx * 4];
            float4 b1 = *(const float4*)&Ws[k][64 + tx * 4];
            float av[8] = {a0.x, a0.y, a0.z, a0.w, a1.x, a1.y, a1.z, a1.w};
            float bv[8] = {b0.x, b0.y, b0.z, b0.w, b1.x, b1.y, b1.z, b1.w};
            #pragma unroll
            for (int i = 0; i < 8; ++i)
                #pragma unroll
                for (int j = 0; j < 8; ++j) c[i][j] += av[i] * bv[j];
        }
    }

    const int mbase = bm * 128, nbase = bn * 128;
    int mi[8], nj[8];
    #pragma unroll
    for (int i = 0; i < 8; ++i) mi[i] = mbase + ((i < 4) ? (ty * 4 + i) : (64 + ty * 4 + i - 4));
    #pragma unroll
    for (int j = 0; j < 8; ++j) nj[j] = nbase + ((j < 4) ? (tx * 4 + j) : (64 + tx * 4 + j - 4));

    if (HAS_LORA) {
        #pragma unroll
        for (int r = 0; r < R_; ++r) {
            float la[8], lb[8];
            #pragma unroll
            for (int i = 0; i < 8; ++i) la[i] = tA[(size_t)mi[i] * R_ + r];
            #pragma unroll
            for (int j = 0; j < 8; ++j) lb[j] = lB[(size_t)nj[j] * R_ + r];
            #pragma unroll
            for (int i = 0; i < 8; ++i)
                #pragma unroll
                for (int j = 0; j < 8; ++j) c[i][j] += 2.0f * la[i] * lb[j];
        }
    }

    #pragma unroll
    for (int i = 0; i < 8; ++i) {
        size_t row = (size_t)mi[i] * Ndim;
        float y0[4], y1[4];
        #pragma unroll
        for (int j = 0; j < 4; ++j) { y0[j] = c[i][j]; y1[j] = c[i][j + 4]; }
        if (ACT == 1) {
            #pragma unroll
            for (int j = 0; j < 4; ++j) { y0[j] = silu_f(y0[j]); y1[j] = silu_f(y1[j]); }
        }
        if (HAS_RESID) {
            float4 r0 = *(const float4*)(resid + row + nbase + tx * 4);
            float4 r1 = *(const float4*)(resid + row + nbase + 64 + tx * 4);
            y0[0] += r0.x; y0[1] += r0.y; y0[2] += r0.z; y0[3] += r0.w;
            y1[0] += r1.x; y1[1] += r1.y; y1[2] += r1.z; y1[3] += r1.w;
        }
        float4 o0 = make_float4(y0[0], y0[1], y0[2], y0[3]);
        float4 o1 = make_float4(y1[0], y1[1], y1[2], y1[3]);
        *(float4*)(Y + row + nbase + tx * 4) = o0;
        *(float4*)(Y + row + nbase + 64 + tx * 4) = o1;
    }
}

// ---------------------------------------------------------------------------
// RoPE applied in place to q and k. Grid: (S, H, 2*B). 128 threads = Dh.
// ---------------------------------------------------------------------------
__global__ __launch_bounds__(128) void rope_kernel(float* __restrict__ q, float* __restrict__ k) {
    int s = blockIdx.x, h = blockIdx.y, bz = blockIdx.z;
    float* buf = (bz < B_) ? q : k;
    int b = bz & 1;
    int d = threadIdx.x;
    size_t base = (((size_t)b * S_ + s) * H_ + h) * DH_;
    int j = d & 63;
    float inv_freq = powf(10000.0f, -((float)j) / 64.0f);
    float ang = (float)s * inv_freq;
    float cv = cosf(ang), sv = sinf(ang);
    float x = buf[base + d];
    float other = (d < 64) ? -buf[base + d + 64] : buf[base + d - 64];
    __syncthreads();
    buf[base + d] = x * cv + other * sv;
}

// ---------------------------------------------------------------------------
// Attention: one block per (q-row, head, batch). 128 threads.
// Exact softmax (max-subtract), scores staged in LDS, causal via loop bound,
// pad mask via -1e9 bias.
// ---------------------------------------------------------------------------
__global__ __launch_bounds__(128) void attn_kernel(const float* __restrict__ q,
                                                   const float* __restrict__ k,
                                                   const float* __restrict__ v,
                                                   const int* __restrict__ mask,
                                                   float* __restrict__ ctx) {
    int qpos = blockIdx.x, h = blockIdx.y, b = blockIdx.z;
    __shared__ float qs[DH_];
    __shared__ float sc[S_];
    __shared__ float red[128];
    int tid = threadIdx.x;
    const float inv = 0.08838834764831845f;  // 1/sqrt(128)
    qs[tid] = q[(((size_t)b * S_ + qpos) * H_ + h) * DH_ + tid] * inv;
    __syncthreads();
    int nk = qpos + 1;
    for (int kp = tid; kp < nk; kp += 128) {
        const float* kr = k + (((size_t)b * S_ + kp) * H_ + h) * DH_;
        float d0 = 0, d1 = 0, d2 = 0, d3 = 0;
        #pragma unroll 8
        for (int d = 0; d < DH_; d += 4) {
            d0 += qs[d] * kr[d];
            d1 += qs[d + 1] * kr[d + 1];
            d2 += qs[d + 2] * kr[d + 2];
            d3 += qs[d + 3] * kr[d + 3];
        }
        float dot = (d0 + d1) + (d2 + d3);
        sc[kp] = mask[(size_t)b * S_ + kp] ? dot : dot - 1e9f;
    }
    __syncthreads();
    float lm = -1e30f;
    for (int kp = tid; kp < nk; kp += 128) lm = fmaxf(lm, sc[kp]);
    red[tid] = lm; __syncthreads();
    for (int s = 64; s > 0; s >>= 1) {
        if (tid < s) red[tid] = fmaxf(red[tid], red[tid + s]);
        __syncthreads();
    }
    float mx = red[0]; __syncthreads();
    float ls = 0.0f;
    for (int kp = tid; kp < nk; kp += 128) {
        float e = expf(sc[kp] - mx);
        sc[kp] = e;
        ls += e;
    }
    red[tid] = ls; __syncthreads();
    for (int s = 64; s > 0; s >>= 1) {
        if (tid < s) red[tid] += red[tid + s];
        __syncthreads();
    }
    float pinv = 1.0f / red[0];
    __syncthreads();
    // ctx accumulation: lane = d (coalesced V reads)
    float a0 = 0, a1 = 0;
    const float* vb = v + (((size_t)b * S_) * H_ + h) * DH_ + tid;
    int kp = 0;
    for (; kp + 1 < nk; kp += 2) {
        a0 += sc[kp] * vb[(size_t)kp * H_ * DH_];
        a1 += sc[kp + 1] * vb[(size_t)(kp + 1) * H_ * DH_];
    }
    if (kp < nk) a0 += sc[kp] * vb[(size_t)kp * H_ * DH_];
    ctx[(((size_t)b * S_ + qpos) * H_ + h) * DH_ + tid] = (a0 + a1) * pinv;
}

// ---------------------------------------------------------------------------
// Elementwise: a *= b
// ---------------------------------------------------------------------------
__global__ void mul_kernel(float* __restrict__ a, const float* __restrict__ b, size_t n) {
    size_t i = (size_t)blockIdx.x * 256 + threadIdx.x;
    if (i < n) a[i] *= b[i];
}

extern "C" void kernel_launch(void* const* d_in, const int* in_sizes, int n_in,
                              void* d_out, int out_size, void* d_ws, size_t ws_size,
                              hipStream_t stream) {
    const float* embeds = (const float*)d_in[0];
    const int*   amask  = (const int*)d_in[1];
    const float* wq = (const float*)d_in[2];
    const float* aq = (const float*)d_in[3];
    const float* bq = (const float*)d_in[4];
    const float* wk = (const float*)d_in[5];
    const float* ak = (const float*)d_in[6];
    const float* bk = (const float*)d_in[7];
    const float* wv = (const float*)d_in[8];
    const float* av = (const float*)d_in[9];
    const float* bv = (const float*)d_in[10];
    const float* wo = (const float*)d_in[11];
    const float* ao = (const float*)d_in[12];
    const float* bo = (const float*)d_in[13];
    const float* ln1 = (const float*)d_in[14];
    const float* wg = (const float*)d_in[15];
    const float* wu = (const float*)d_in[16];
    const float* wd = (const float*)d_in[17];
    const float* ln2 = (const float*)d_in[18];
    const float* normf = (const float*)d_in[19];
    float* outp = (float*)d_out;

    float* p = (float*)d_ws;
    float* x    = p; p += (size_t)M_ * D_;
    float* h    = p; p += (size_t)M_ * D_;
    float* qb   = p; p += (size_t)M_ * D_;
    float* kb   = p; p += (size_t)M_ * D_;
    float* vb   = p; p += (size_t)M_ * D_;
    float* ctx  = p; p += (size_t)M_ * D_;
    float* tA   = p; p += (size_t)M_ * R_;
    float* gate = p; p += (size_t)M_ * F_;
    float* up   = p; p += (size_t)M_ * F_;
    float* am_q = p; p += (size_t)LAYERS * D_ * (D_ / 64);
    float* am_k = p; p += (size_t)LAYERS * D_ * (D_ / 64);
    float* am_v = p; p += (size_t)LAYERS * D_ * (D_ / 64);
    float* am_o = p; p += (size_t)LAYERS * D_ * (D_ / 64);
    float* am_g = p; p += (size_t)LAYERS * F_ * (D_ / 64);
    float* am_u = p; p += (size_t)LAYERS * F_ * (D_ / 64);
    float* am_d = p; p += (size_t)LAYERS * D_ * (F_ / 64);

    // x <- inputs_embeds
    hipMemcpyAsync(x, embeds, (size_t)M_ * D_ * sizeof(float),
                   hipMemcpyDeviceToDevice, stream);

    // Per-64-block absmax for all weights (both layers at once).
    {
        int nb_dd = LAYERS * D_ * (D_ / 64);   // 131072
        int nb_fd = LAYERS * F_ * (D_ / 64);   // 352256
        int nb_df = LAYERS * D_ * (F_ / 64);   // 352256
        absmax_kernel<<<(nb_dd + 255) / 256, 256, 0, stream>>>(wq, am_q, nb_dd);
        absmax_kernel<<<(nb_dd + 255) / 256, 256, 0, stream>>>(wk, am_k, nb_dd);
        absmax_kernel<<<(nb_dd + 255) / 256, 256, 0, stream>>>(wv, am_v, nb_dd);
        absmax_kernel<<<(nb_dd + 255) / 256, 256, 0, stream>>>(wo, am_o, nb_dd);
        absmax_kernel<<<(nb_fd + 255) / 256, 256, 0, stream>>>(wg, am_g, nb_fd);
        absmax_kernel<<<(nb_fd + 255) / 256, 256, 0, stream>>>(wu, am_u, nb_fd);
        absmax_kernel<<<(nb_df + 255) / 256, 256, 0, stream>>>(wd, am_d, nb_df);
    }

    const dim3 gemmDD(D_ / 128, M_ / 128);  // (16,16)
    const dim3 gemmFD(F_ / 128, M_ / 128);  // (43,16)

    for (int l = 0; l < LAYERS; ++l) {
        const float* wq_l = wq + (size_t)l * D_ * D_;
        const float* wk_l = wk + (size_t)l * D_ * D_;
        const float* wv_l = wv + (size_t)l * D_ * D_;
        const float* wo_l = wo + (size_t)l * D_ * D_;
        const float* aq_l = aq + (size_t)l * R_ * D_;
        const float* ak_l = ak + (size_t)l * R_ * D_;
        const float* av_l = av + (size_t)l * R_ * D_;
        const float* ao_l = ao + (size_t)l * R_ * D_;
        const float* bq_l = bq + (size_t)l * D_ * R_;
        const float* bk_l = bk + (size_t)l * D_ * R_;
        const float* bv_l = bv + (size_t)l * D_ * R_;
        const float* bo_l = bo + (size_t)l * D_ * R_;
        const float* ln1_l = ln1 + (size_t)l * D_;
        const float* ln2_l = ln2 + (size_t)l * D_;
        const float* wg_l = wg + (size_t)l * F_ * D_;
        const float* wu_l = wu + (size_t)l * F_ * D_;
        const float* wd_l = wd + (size_t)l * D_ * F_;
        const float* amq_l = am_q + (size_t)l * D_ * (D_ / 64);
        const float* amk_l = am_k + (size_t)l * D_ * (D_ / 64);
        const float* amv_l = am_v + (size_t)l * D_ * (D_ / 64);
        const float* amo_l = am_o + (size_t)l * D_ * (D_ / 64);
        const float* amg_l = am_g + (size_t)l * F_ * (D_ / 64);
        const float* amu_l = am_u + (size_t)l * F_ * (D_ / 64);
        const float* amd_l = am_d + (size_t)l * D_ * (F_ / 64);

        // h = rms_norm(x, ln1)
        rmsnorm_kernel<<<M_, 256, 0, stream>>>(x, ln1_l, h);

        // q/k/v projections (QLoRA)
        lora_a_kernel<<<M_, 256, 0, stream>>>(h, aq_l, tA);
        gemm_qlora_kernel<0, true, false><<<gemmDD, 256, 0, stream>>>(
            h, wq_l, amq_l, tA, bq_l, nullptr, qb, M_, D_, D_);
        lora_a_kernel<<<M_, 256, 0, stream>>>(h, ak_l, tA);
        gemm_qlora_kernel<0, true, false><<<gemmDD, 256, 0, stream>>>(
            h, wk_l, amk_l, tA, bk_l, nullptr, kb, M_, D_, D_);
        lora_a_kernel<<<M_, 256, 0, stream>>>(h, av_l, tA);
        gemm_qlora_kernel<0, true, false><<<gemmDD, 256, 0, stream>>>(
            h, wv_l, amv_l, tA, bv_l, nullptr, vb, M_, D_, D_);

        // RoPE on q, k
        rope_kernel<<<dim3(S_, H_, 2 * B_), 128, 0, stream>>>(qb, kb);

        // attention
        attn_kernel<<<dim3(S_, H_, B_), 128, 0, stream>>>(qb, kb, vb, amask, ctx);

        // o-projection + residual: x = x + qlora(ctx, wo)
        lora_a_kernel<<<M_, 256, 0, stream>>>(ctx, ao_l, tA);
        gemm_qlora_kernel<0, true, true><<<gemmDD, 256, 0, stream>>>(
            ctx, wo_l, amo_l, tA, bo_l, x, x, M_, D_, D_);

        // MLP
        rmsnorm_kernel<<<M_, 256, 0, stream>>>(x, ln2_l, h);
        gemm_qlora_kernel<1, false, false><<<gemmFD, 256, 0, stream>>>(
            h, wg_l, amg_l, nullptr, nullptr, nullptr, gate, M_, F_, D_);
        gemm_qlora_kernel<0, false, false><<<gemmFD, 256, 0, stream>>>(
            h, wu_l, amu_l, nullptr, nullptr, nullptr, up, M_, F_, D_);
        mul_kernel<<<(int)(((size_t)M_ * F_ + 255) / 256), 256, 0, stream>>>(
            gate, up, (size_t)M_ * F_);
        gemm_qlora_kernel<0, false, true><<<gemmDD, 256, 0, stream>>>(
            gate, wd_l, amd_l, nullptr, nullptr, x, x, M_, D_, F_);
    }

    // final norm -> output
    rmsnorm_kernel<<<M_, 256, 0, stream>>>(x, normf, outp);
}

// Round 2
// 4140.601 us; speedup vs baseline: 2.9307x; 2.9307x over previous
//
#include <hip/hip_runtime.h>
#include <math.h>

#define LAYERS 2
#define B_ 2
#define S_ 1024
#define D_ 2048
#define F_ 5504
#define R_ 8
#define H_ 16
#define DH_ 128
#define M_ (B_*S_)   // 2048

typedef __attribute__((ext_vector_type(8))) short bf16x8;
typedef __attribute__((ext_vector_type(4))) float f32x4;

__device__ __forceinline__ float bf2f(unsigned short h) {
    unsigned u = ((unsigned)h) << 16;
    return __builtin_bit_cast(float, u);
}
__device__ __forceinline__ unsigned short f2bf(float f) {
    unsigned u = __builtin_bit_cast(unsigned, f);
    u += 0x7fffu + ((u >> 16) & 1u);
    return (unsigned short)(u >> 16);
}

// NF4: idx = searchsorted(mids, normed, left) == count(mids < normed)
__device__ __forceinline__ float nf4_deq(float v, float amax) {
    const float C0  = -1.0f;
    const float C1  = -0.6961928009986877f;
    const float C2  = -0.5250730514526367f;
    const float C3  = -0.39491748809814453f;
    const float C4  = -0.28444138169288635f;
    const float C5  = -0.18477343022823334f;
    const float C6  = -0.09105003625154495f;
    const float C7  = 0.0f;
    const float C8  = 0.07958029955625534f;
    const float C9  = 0.16093020141124725f;
    const float C10 = 0.24611230194568634f;
    const float C11 = 0.33791524171829224f;
    const float C12 = 0.44070982933044434f;
    const float C13 = 0.5626170039176941f;
    const float C14 = 0.7229568362236023f;
    const float C15 = 1.0f;
    float normed = v / fmaxf(amax, 1e-12f);
    float c = C0;
    c = (normed > 0.5f*(C0 +C1 )) ? C1  : c;
    c = (normed > 0.5f*(C1 +C2 )) ? C2  : c;
    c = (normed > 0.5f*(C2 +C3 )) ? C3  : c;
    c = (normed > 0.5f*(C3 +C4 )) ? C4  : c;
    c = (normed > 0.5f*(C4 +C5 )) ? C5  : c;
    c = (normed > 0.5f*(C5 +C6 )) ? C6  : c;
    c = (normed > 0.5f*(C6 +C7 )) ? C7  : c;
    c = (normed > 0.5f*(C7 +C8 )) ? C8  : c;
    c = (normed > 0.5f*(C8 +C9 )) ? C9  : c;
    c = (normed > 0.5f*(C9 +C10)) ? C10 : c;
    c = (normed > 0.5f*(C10+C11)) ? C11 : c;
    c = (normed > 0.5f*(C11+C12)) ? C12 : c;
    c = (normed > 0.5f*(C12+C13)) ? C13 : c;
    c = (normed > 0.5f*(C13+C14)) ? C14 : c;
    c = (normed > 0.5f*(C14+C15)) ? C15 : c;
    return c * amax;
}

__device__ __forceinline__ float silu_f(float x) { return x / (1.0f + expf(-x)); }

// ---------------------------------------------------------------------------
// Fused NF4 fake-quant: per-64-block absmax + dequant + bf16 cast.
// One wave per 64-elem block; 4 waves per workgroup.
// ---------------------------------------------------------------------------
__global__ __launch_bounds__(256) void dequant_bf16_kernel(
        const float* __restrict__ w, unsigned short* __restrict__ out, int nblk) {
    int b = blockIdx.x * 4 + (threadIdx.x >> 6);
    if (b >= nblk) return;
    int lane = threadIdx.x & 63;
    size_t idx = (size_t)b * 64 + lane;
    float v = w[idx];
    float m = fabsf(v);
    #pragma unroll
    for (int off = 32; off > 0; off >>= 1) m = fmaxf(m, __shfl_xor(m, off));
    out[idx] = f2bf(nf4_deq(v, m));
}

// ---------------------------------------------------------------------------
// RMSNorm: fp32 in, bf16 or fp32 out.
// ---------------------------------------------------------------------------
template<bool BF16OUT>
__global__ __launch_bounds__(256) void rmsnorm_kernel(const float* __restrict__ x,
                                                      const float* __restrict__ w,
                                                      void* __restrict__ out) {
    int row = blockIdx.x;
    const float* xr = x + (size_t)row * D_;
    float ss = 0.0f;
    for (int k = threadIdx.x; k < D_; k += 256) { float v = xr[k]; ss += v * v; }
    __shared__ float red[256];
    red[threadIdx.x] = ss; __syncthreads();
    for (int s = 128; s > 0; s >>= 1) {
        if (threadIdx.x < s) red[threadIdx.x] += red[threadIdx.x + s];
        __syncthreads();
    }
    float scale = 1.0f / sqrtf(red[0] / (float)D_ + 1e-5f);
    for (int k = threadIdx.x; k < D_; k += 256) {
        float v = xr[k] * scale * w[k];
        if (BF16OUT) ((unsigned short*)out)[(size_t)row * D_ + k] = f2bf(v);
        else         ((float*)out)[(size_t)row * D_ + k] = v;
    }
}

// ---------------------------------------------------------------------------
// LoRA A-projection: tA[m][r] = sum_k h[m,k] * A[r,k], h in bf16.
// ---------------------------------------------------------------------------
__global__ __launch_bounds__(256) void lora_a_kernel(const unsigned short* __restrict__ h,
                                                     const float* __restrict__ A,
                                                     float* __restrict__ tA) {
    int m = blockIdx.x;
    const unsigned short* hr = h + (size_t)m * D_;
    float acc[R_];
    #pragma unroll
    for (int r = 0; r < R_; ++r) acc[r] = 0.0f;
    for (int k = threadIdx.x; k < D_; k += 256) {
        float hv = bf2f(hr[k]);
        #pragma unroll
        for (int r = 0; r < R_; ++r) acc[r] += hv * A[(size_t)r * D_ + k];
    }
    __shared__ float red[256];
    for (int r = 0; r < R_; ++r) {
        red[threadIdx.x] = acc[r]; __syncthreads();
        for (int s = 128; s > 0; s >>= 1) {
            if (threadIdx.x < s) red[threadIdx.x] += red[threadIdx.x + s];
            __syncthreads();
        }
        if (threadIdx.x == 0) tA[(size_t)m * R_ + r] = red[0];
        __syncthreads();
    }
}

// ---------------------------------------------------------------------------
// MFMA bf16 GEMM, m97 structure: 128x128 tile, BK=32, 4 waves (2x2 of 64x64),
// each wave 4x4 grid of 16x16x32 MFMA. global_load_lds width=16 staging.
// Supports up to 3 fused weight tensors sharing the same X (QKV).
// Y[m,n] = sum_k X[m,k]*W[n,k] [+2*sum_r tA[m,r]*lB[n,r]] [silu] [+resid]
// ---------------------------------------------------------------------------
struct GemmPtrs {
    const unsigned short* W[3];
    const float* tA[3];
    const float* lB[3];
    void* Y[3];
};

__device__ __forceinline__ void load_lds16(const void* g, void* l) {
    __builtin_amdgcn_global_load_lds(
        (__attribute__((address_space(1))) void*)g,
        (__attribute__((address_space(3))) void*)l, 16, 0, 0);
}

template<int ACT, bool HAS_LORA, bool HAS_RESID, bool OUT_BF16>
__global__ __launch_bounds__(256) void gemm_mfma_kernel(
        const unsigned short* __restrict__ X, GemmPtrs P,
        const float* __restrict__ resid,
        int Kdim, int Ndim, int nbper) {
    __shared__ __align__(16) unsigned short As[128 * 32];
    __shared__ __align__(16) unsigned short Bs[128 * 32];

    const int tid  = threadIdx.x;
    const int lane = tid & 63;
    const int wave = tid >> 6;
    int bn = blockIdx.x;
    const int bm = blockIdx.y;
    const int sel = bn / nbper;
    bn -= sel * nbper;

    const unsigned short* W = P.W[sel];

    const int wm = (wave & 1) * 64;
    const int wn = (wave >> 1) * 64;

    f32x4 acc[4][4] = {};

    const int lrow = lane >> 2;        // 0..15
    const int lcol = (lane & 3) * 8;   // 0,8,16,24 (shorts)
    const unsigned short* Ag = X + (size_t)(bm * 128) * Kdim;
    const unsigned short* Wg = W + (size_t)(bn * 128) * Kdim;
    const unsigned short* a0 = Ag + (size_t)(wave * 16 + lrow) * Kdim + lcol;
    const unsigned short* a1 = Ag + (size_t)(64 + wave * 16 + lrow) * Kdim + lcol;
    const unsigned short* b0 = Wg + (size_t)(wave * 16 + lrow) * Kdim + lcol;
    const unsigned short* b1 = Wg + (size_t)(64 + wave * 16 + lrow) * Kdim + lcol;
    unsigned short* lA0 = &As[(wave * 16) * 32];
    unsigned short* lA1 = &As[(64 + wave * 16) * 32];
    unsigned short* lB0 = &Bs[(wave * 16) * 32];
    unsigned short* lB1 = &Bs[(64 + wave * 16) * 32];

    const int fr = lane & 15;
    const int fk = (lane >> 4) * 8;

    for (int kt = 0; kt < Kdim; kt += 32) {
        __syncthreads();
        load_lds16(a0 + kt, lA0);
        load_lds16(a1 + kt, lA1);
        load_lds16(b0 + kt, lB0);
        load_lds16(b1 + kt, lB1);
        __syncthreads();
        bf16x8 af[4], bf[4];
        #pragma unroll
        for (int i = 0; i < 4; ++i)
            af[i] = *(const bf16x8*)&As[(wm + i * 16 + fr) * 32 + fk];
        #pragma unroll
        for (int j = 0; j < 4; ++j)
            bf[j] = *(const bf16x8*)&Bs[(wn + j * 16 + fr) * 32 + fk];
        #pragma unroll
        for (int i = 0; i < 4; ++i)
            #pragma unroll
            for (int j = 0; j < 4; ++j)
                acc[i][j] = __builtin_amdgcn_mfma_f32_16x16x32_bf16(
                    af[i], bf[j], acc[i][j], 0, 0, 0);
    }

    // Epilogue. C/D layout: col = lane&15, row = (lane>>4)*4 + reg.
    const int colq = bn * 128 + wn + fr;
    const int rowq = bm * 128 + wm + (lane >> 4) * 4;

    float lbv[4][R_];
    if (HAS_LORA) {
        const float* lB = P.lB[sel];
        #pragma unroll
        for (int j = 0; j < 4; ++j)
            #pragma unroll
            for (int rr = 0; rr < R_; ++rr)
                lbv[j][rr] = lB[(size_t)(colq + j * 16) * R_ + rr];
    }

    #pragma unroll
    for (int i = 0; i < 4; ++i) {
        #pragma unroll
        for (int r = 0; r < 4; ++r) {
            const int row = rowq + i * 16 + r;
            float lam[R_];
            if (HAS_LORA) {
                const float* tA = P.tA[sel];
                #pragma unroll
                for (int rr = 0; rr < R_; ++rr) lam[rr] = tA[(size_t)row * R_ + rr];
            }
            #pragma unroll
            for (int j = 0; j < 4; ++j) {
                float v = acc[i][j][r];
                if (HAS_LORA) {
                    #pragma unroll
                    for (int rr = 0; rr < R_; ++rr) v += 2.0f * lam[rr] * lbv[j][rr];
                }
                if (ACT == 1) v = silu_f(v);
                const int col = colq + j * 16;
                size_t off = (size_t)row * Ndim + col;
                if (HAS_RESID) v += resid[off];
                if (OUT_BF16) ((unsigned short*)P.Y[sel])[off] = f2bf(v);
                else          ((float*)P.Y[sel])[off] = v;
            }
        }
    }
}

// ---------------------------------------------------------------------------
// RoPE in place on q,k (fp32). Grid (S, H, 2*B), 128 threads.
// ---------------------------------------------------------------------------
__global__ __launch_bounds__(128) void rope_kernel(float* __restrict__ q, float* __restrict__ k) {
    int s = blockIdx.x, h = blockIdx.y, bz = blockIdx.z;
    float* buf = (bz < B_) ? q : k;
    int b = bz & 1;
    int d = threadIdx.x;
    size_t base = (((size_t)b * S_ + s) * H_ + h) * DH_;
    int j = d & 63;
    float inv_freq = powf(10000.0f, -((float)j) / 64.0f);
    float ang = (float)s * inv_freq;
    float cv = cosf(ang), sv = sinf(ang);
    float x = buf[base + d];
    float other = (d < 64) ? -buf[base + d + 64] : buf[base + d - 64];
    __syncthreads();
    buf[base + d] = x * cv + other * sv;
}

// ---------------------------------------------------------------------------
// Attention (unchanged structure; ctx written bf16 for the o-proj GEMM).
// ---------------------------------------------------------------------------
__global__ __launch_bounds__(128) void attn_kernel(const float* __restrict__ q,
                                                   const float* __restrict__ k,
                                                   const float* __restrict__ v,
                                                   const int* __restrict__ mask,
                                                   unsigned short* __restrict__ ctx) {
    int qpos = blockIdx.x, h = blockIdx.y, b = blockIdx.z;
    __shared__ float qs[DH_];
    __shared__ float sc[S_];
    __shared__ float red[128];
    int tid = threadIdx.x;
    const float inv = 0.08838834764831845f;  // 1/sqrt(128)
    qs[tid] = q[(((size_t)b * S_ + qpos) * H_ + h) * DH_ + tid] * inv;
    __syncthreads();
    int nk = qpos + 1;
    for (int kp = tid; kp < nk; kp += 128) {
        const float* kr = k + (((size_t)b * S_ + kp) * H_ + h) * DH_;
        float d0 = 0, d1 = 0, d2 = 0, d3 = 0;
        #pragma unroll 8
        for (int d = 0; d < DH_; d += 4) {
            d0 += qs[d] * kr[d];
            d1 += qs[d + 1] * kr[d + 1];
            d2 += qs[d + 2] * kr[d + 2];
            d3 += qs[d + 3] * kr[d + 3];
        }
        float dot = (d0 + d1) + (d2 + d3);
        sc[kp] = mask[(size_t)b * S_ + kp] ? dot : dot - 1e9f;
    }
    __syncthreads();
    float lm = -1e30f;
    for (int kp = tid; kp < nk; kp += 128) lm = fmaxf(lm, sc[kp]);
    red[tid] = lm; __syncthreads();
    for (int s = 64; s > 0; s >>= 1) {
        if (tid < s) red[tid] = fmaxf(red[tid], red[tid + s]);
        __syncthreads();
    }
    float mx = red[0]; __syncthreads();
    float ls = 0.0f;
    for (int kp = tid; kp < nk; kp += 128) {
        float e = expf(sc[kp] - mx);
        sc[kp] = e;
        ls += e;
    }
    red[tid] = ls; __syncthreads();
    for (int s = 64; s > 0; s >>= 1) {
        if (tid < s) red[tid] += red[tid + s];
        __syncthreads();
    }
    float pinv = 1.0f / red[0];
    __syncthreads();
    float a0 = 0, a1 = 0;
    const float* vb = v + (((size_t)b * S_) * H_ + h) * DH_ + tid;
    int kp = 0;
    for (; kp + 1 < nk; kp += 2) {
        a0 += sc[kp] * vb[(size_t)kp * H_ * DH_];
        a1 += sc[kp + 1] * vb[(size_t)(kp + 1) * H_ * DH_];
    }
    if (kp < nk) a0 += sc[kp] * vb[(size_t)kp * H_ * DH_];
    ctx[(((size_t)b * S_ + qpos) * H_ + h) * DH_ + tid] = f2bf((a0 + a1) * pinv);
}

// ---------------------------------------------------------------------------
// In-place: gate[i] = bf16(gate[i] * up[i])   (silu already applied in GEMM)
// ---------------------------------------------------------------------------
__global__ void mul_kernel(unsigned short* __restrict__ a,
                           const unsigned short* __restrict__ b, size_t n) {
    size_t i = (size_t)blockIdx.x * 256 + threadIdx.x;
    if (i < n) a[i] = f2bf(bf2f(a[i]) * bf2f(b[i]));
}

extern "C" void kernel_launch(void* const* d_in, const int* in_sizes, int n_in,
                              void* d_out, int out_size, void* d_ws, size_t ws_size,
                              hipStream_t stream) {
    const float* embeds = (const float*)d_in[0];
    const int*   amask  = (const int*)d_in[1];
    const float* wq = (const float*)d_in[2];
    const float* aq = (const float*)d_in[3];
    const float* bq = (const float*)d_in[4];
    const float* wk = (const float*)d_in[5];
    const float* ak = (const float*)d_in[6];
    const float* bk = (const float*)d_in[7];
    const float* wv = (const float*)d_in[8];
    const float* av = (const float*)d_in[9];
    const float* bv = (const float*)d_in[10];
    const float* wo = (const float*)d_in[11];
    const float* ao = (const float*)d_in[12];
    const float* bo = (const float*)d_in[13];
    const float* ln1 = (const float*)d_in[14];
    const float* wg = (const float*)d_in[15];
    const float* wu = (const float*)d_in[16];
    const float* wd = (const float*)d_in[17];
    const float* ln2 = (const float*)d_in[18];
    const float* normf = (const float*)d_in[19];
    float* outp = (float*)d_out;

    const size_t DD = (size_t)D_ * D_;     // 4.19M
    const size_t FD = (size_t)F_ * D_;     // 11.27M

    char* p = (char*)d_ws;
    unsigned short* wbuf = (unsigned short*)p; p += 3 * DD * sizeof(unsigned short); // 25.2 MB (holds QKV, or wg/wu/wd singly)
    float* x    = (float*)p;          p += (size_t)M_ * D_ * sizeof(float);
    unsigned short* h = (unsigned short*)p; p += (size_t)M_ * D_ * sizeof(unsigned short);
    float* qb   = (float*)p;          p += (size_t)M_ * D_ * sizeof(float);
    float* kb   = (float*)p;          p += (size_t)M_ * D_ * sizeof(float);
    float* vbuf = (float*)p;          p += (size_t)M_ * D_ * sizeof(float);
    unsigned short* ctx = (unsigned short*)p; p += (size_t)M_ * D_ * sizeof(unsigned short);
    unsigned short* gate = (unsigned short*)p; p += (size_t)M_ * F_ * sizeof(unsigned short);
    unsigned short* up   = (unsigned short*)p; p += (size_t)M_ * F_ * sizeof(unsigned short);
    float* tA0 = (float*)p; p += (size_t)M_ * R_ * sizeof(float);
    float* tA1 = (float*)p; p += (size_t)M_ * R_ * sizeof(float);
    float* tA2 = (float*)p; p += (size_t)M_ * R_ * sizeof(float);

    hipMemcpyAsync(x, embeds, (size_t)M_ * D_ * sizeof(float),
                   hipMemcpyDeviceToDevice, stream);

    const int DDblk = (int)(DD / 64);   // 65536
    const int FDblk = (int)(FD / 64);   // 176128

    for (int l = 0; l < LAYERS; ++l) {
        const float* wq_l = wq + l * DD;
        const float* wk_l = wk + l * DD;
        const float* wv_l = wv + l * DD;
        const float* wo_l = wo + l * DD;
        const float* aq_l = aq + (size_t)l * R_ * D_;
        const float* ak_l = ak + (size_t)l * R_ * D_;
        const float* av_l = av + (size_t)l * R_ * D_;
        const float* ao_l = ao + (size_t)l * R_ * D_;
        const float* bq_l = bq + (size_t)l * D_ * R_;
        const float* bk_l = bk + (size_t)l * D_ * R_;
        const float* bv_l = bv + (size_t)l * D_ * R_;
        const float* bo_l = bo + (size_t)l * D_ * R_;
        const float* ln1_l = ln1 + (size_t)l * D_;
        const float* ln2_l = ln2 + (size_t)l * D_;
        const float* wg_l = wg + l * FD;
        const float* wu_l = wu + l * FD;
        const float* wd_l = wd + l * FD;

        // ---- attention block ----
        rmsnorm_kernel<true><<<M_, 256, 0, stream>>>(x, ln1_l, h);

        dequant_bf16_kernel<<<(DDblk + 3) / 4, 256, 0, stream>>>(wq_l, wbuf, DDblk);
        dequant_bf16_kernel<<<(DDblk + 3) / 4, 256, 0, stream>>>(wk_l, wbuf + DD, DDblk);
        dequant_bf16_kernel<<<(DDblk + 3) / 4, 256, 0, stream>>>(wv_l, wbuf + 2 * DD, DDblk);

        lora_a_kernel<<<M_, 256, 0, stream>>>(h, aq_l, tA0);
        lora_a_kernel<<<M_, 256, 0, stream>>>(h, ak_l, tA1);
        lora_a_kernel<<<M_, 256, 0, stream>>>(h, av_l, tA2);

        {
            GemmPtrs P;
            P.W[0] = wbuf; P.W[1] = wbuf + DD; P.W[2] = wbuf + 2 * DD;
            P.tA[0] = tA0; P.tA[1] = tA1; P.tA[2] = tA2;
            P.lB[0] = bq_l; P.lB[1] = bk_l; P.lB[2] = bv_l;
            P.Y[0] = qb; P.Y[1] = kb; P.Y[2] = vbuf;
            gemm_mfma_kernel<0, true, false, false><<<dim3(48, 16), 256, 0, stream>>>(
                h, P, nullptr, D_, D_, 16);
        }

        rope_kernel<<<dim3(S_, H_, 2 * B_), 128, 0, stream>>>(qb, kb);
        attn_kernel<<<dim3(S_, H_, B_), 128, 0, stream>>>(qb, kb, vbuf, amask, ctx);

        // o-projection + residual into x
        dequant_bf16_kernel<<<(DDblk + 3) / 4, 256, 0, stream>>>(wo_l, wbuf, DDblk);
        lora_a_kernel<<<M_, 256, 0, stream>>>(ctx, ao_l, tA0);
        {
            GemmPtrs P = {};
            P.W[0] = wbuf; P.tA[0] = tA0; P.lB[0] = bo_l; P.Y[0] = x;
            gemm_mfma_kernel<0, true, true, false><<<dim3(16, 16), 256, 0, stream>>>(
                ctx, P, x, D_, D_, 16);
        }

        // ---- MLP block ----
        rmsnorm_kernel<true><<<M_, 256, 0, stream>>>(x, ln2_l, h);

        dequant_bf16_kernel<<<(FDblk + 3) / 4, 256, 0, stream>>>(wg_l, wbuf, FDblk);
        {
            GemmPtrs P = {};
            P.W[0] = wbuf; P.Y[0] = gate;
            gemm_mfma_kernel<1, false, false, true><<<dim3(43, 16), 256, 0, stream>>>(
                h, P, nullptr, D_, F_, 43);
        }
        dequant_bf16_kernel<<<(FDblk + 3) / 4, 256, 0, stream>>>(wu_l, wbuf, FDblk);
        {
            GemmPtrs P = {};
            P.W[0] = wbuf; P.Y[0] = up;
            gemm_mfma_kernel<0, false, false, true><<<dim3(43, 16), 256, 0, stream>>>(
                h, P, nullptr, D_, F_, 43);
        }
        mul_kernel<<<(int)(((size_t)M_ * F_ + 255) / 256), 256, 0, stream>>>(
            gate, up, (size_t)M_ * F_);

        dequant_bf16_kernel<<<(FDblk + 3) / 4, 256, 0, stream>>>(wd_l, wbuf, FDblk);
        {
            GemmPtrs P = {};
            P.W[0] = wbuf; P.Y[0] = x;
            gemm_mfma_kernel<0, false, true, false><<<dim3(16, 16), 256, 0, stream>>>(
                gate, P, x, F_, D_, 16);
        }
    }

    rmsnorm_kernel<false><<<M_, 256, 0, stream>>>(x, normf, outp);
}